// Round 18
// baseline (499.873 us; speedup 1.0000x reference)
//
#include <hip/hip_runtime.h>
#include <math.h>

// SingleGAP: per-point tiny MLPs + GLOBAL softmax over N (axis 0, faithful bug),
// then attention-weighted sum. out0 = [N][16] x_attn, out1 = [N][160] h2 (flat,
// [F][K] order per point == x2v raw reshape).
//
// K1 (R18 = R17 + packed-store transpose): the session-invariant ~3.3 TB/s K1
//     wall is STORE-REQUEST rate: 8B/lane@40B-stride h2 stores issue ~200
//     partial-line requests per wave-iter (bytes merge in L2, requests don't).
//     Fix: after the compute reads, the wave's 4 tile rows in buf[cur] are dead
//     -> overwrite them with acc in h2 layout (5 ds_write_b64, data-dep ordered
//     after reads), wave_barrier, read back linearly, store 3 fully-packed
//     float4/lane (1KB/instr, 16 line-requests) -> ~50 requests/wave-iter.
// K2: reduce per-block (m,s) -> global (m,s) per k-slot.
// K3: quad-per-point weighted sum: out0 = softmax(logits) @ x2v (packed I/O).

#define TPTS 16              // points per tile
#define ROWF 164             // padded floats per point row (40 float4 + 1 pad)

__device__ __forceinline__ void comb(float& m, float& s, float om, float os) {
  float M = fmaxf(m, om);
  if (M == -INFINITY) return;  // both empty
  s = s * __expf(m - M) + os * __expf(om - M);
  m = M;
}

// DPP move (VALU): result[lane] = v[ctrl-mapped lane].
template <int CTRL>
__device__ __forceinline__ float dppmov(float v) {
  return __int_as_float(__builtin_amdgcn_update_dpp(
      0, __float_as_int(v), CTRL, 0xf, 0xf, true));
}

// 16-lane butterfly sum, all-DPP (verified R13/R15/R16/R17).
__device__ __forceinline__ float sum16(float v) {
  v += dppmov<0xB1>(v);
  v += dppmov<0x4E>(v);
  v += dppmov<0x141>(v);
  v += dppmov<0x140>(v);
  return v;
}

__device__ __forceinline__ float f4e(const float4& v, int e) {
  return (e == 0) ? v.x : (e == 1) ? v.y : (e == 2) ? v.z : v.w;
}

__global__ __launch_bounds__(256) void gap_k1(
    const float* __restrict__ xknn, const float* __restrict__ x,
    const float* __restrict__ Wf, const float* __restrict__ bf,
    const float* __restrict__ W1, const float* __restrict__ b1p,
    float* __restrict__ out, float* __restrict__ partials, int n) {
  __shared__ float sm[2][TPTS * ROWF];   // 2 x 16 x 164 floats = 21 KB
  __shared__ float s_red[4][10][2];

  const int tid = threadIdx.x;
  const int lane = tid & 63;
  const int wave = tid >> 6;
  const int f = lane & 15;      // owned feature
  const int g = tid >> 4;       // point-in-tile 0..15

  // staging geometry (fixed per thread): F4 indices tid, tid+256, tid+512(<640)
  const int F0 = tid, F1 = tid + 256, F2 = tid + 512;
  const unsigned l0 = (unsigned)((F0 / 40) * ROWF + (F0 % 40) * 4);
  const unsigned l1 = (unsigned)((F1 / 40) * ROWF + (F1 % 40) * 4);
  const unsigned l2 = (unsigned)((F2 / 40) * ROWF + (F2 % 40) * 4);
  const bool has2 = (F2 < TPTS * 40);    // tid < 128

  // packed-readback geometry (fixed per thread): rounds c=0,1,2 cover the
  // wave's 4 points x 40 float4; idx_c = 64c + lane, p = idx/40, s = idx%40
  const int i0r = lane, i1r = lane + 64, i2r = lane + 128;
  const int p0r = i0r / 40, s0r = i0r - 40 * p0r;
  const int p1r = i1r / 40, s1r = i1r - 40 * p1r;
  const int p2r = i2r / 40, s2r = i2r - 40 * p2r;
  const bool hr2 = (i2r < 160);          // lane < 32
  const unsigned rb0 = (unsigned)((wave * 4 + p0r) * ROWF + 4 * s0r);
  const unsigned rb1 = (unsigned)((wave * 4 + p1r) * ROWF + 4 * s1r);
  const unsigned rb2 = (unsigned)((wave * 4 + p2r) * ROWF + 4 * s2r);
  const unsigned gb0 = (unsigned)((wave * 4 + p0r) * 160 + 4 * s0r);
  const unsigned gb1 = (unsigned)((wave * 4 + p1r) * 160 + 4 * s1r);
  const unsigned gb2 = (unsigned)((wave * 4 + p2r) * 160 + 4 * s2r);

  // own Wf row f (16 VGPR), W1[f], bf[f]
  float wfo[16];
#pragma unroll
  for (int dq = 0; dq < 4; ++dq) {
    float4 v = *(const float4*)(Wf + f * 16 + 4 * dq);
    wfo[4 * dq + 0] = v.x;
    wfo[4 * dq + 1] = v.y;
    wfo[4 * dq + 2] = v.z;
    wfo[4 * dq + 3] = v.w;
  }
  const float w1o = W1[f];
  const float bfo = bf[f];
  float u_own = 0.f;   // u[f] = sum_j W1[j] Wf[j][f]
#pragma unroll
  for (int j = 0; j < 16; ++j) u_own = fmaf(W1[j], Wf[j * 16 + f], u_own);
  const float addA = 2.0f * b1p[0];  // global +sb shift is softmax-invariant

  float rm = -INFINITY, rs = 0.f;    // online (m,s) for k == f (f<10)

  float* out0 = out;                       // [n][16]  (logits now, x_attn later)
  float* out1 = out + (size_t)n * 16;      // [n][160] h2 flat ([F][K] per point)

  const long ntiles = (long)n / TPTS;      // n = 1M: exact
  const long G = gridDim.x;
  long t = (long)blockIdx.x;
  int cur = 0;

  // NAMED staging regs (R14 lesson: arrays trip promote-alloca)
  float4 st0, st1, st2;

  // prologue: stage first tile into buf 0
  {
    const float* src = xknn + (size_t)t * (TPTS * 160);
    st0 = *(const float4*)(src + 4 * F0);
    st1 = *(const float4*)(src + 4 * F1);
    st2 = st0;
    if (has2) st2 = *(const float4*)(src + 4 * F2);
    *(float4*)(&sm[0][l0]) = st0;
    *(float4*)(&sm[0][l1]) = st1;
    if (has2) *(float4*)(&sm[0][l2]) = st2;
  }

  for (; t < ntiles; t += G) {
    __syncthreads();                  // buf[cur] staged & prior readers done

    const long tn = t + G;
    const bool more = (tn < ntiles);
    if (more) {                       // issue-early: in flight under compute
      const float* src = xknn + (size_t)tn * (TPTS * 160);
      st0 = *(const float4*)(src + 4 * F0);
      st1 = *(const float4*)(src + 4 * F1);
      if (has2) st2 = *(const float4*)(src + 4 * F2);
    }

    // ---- compute point pt = t*16 + g from buf[cur] ----
    const unsigned pt = (unsigned)t * TPTS + (unsigned)g;
    const float* sp = &sm[cur][g * ROWF];
    const float xo = x[(size_t)pt * 16 + f];

    float acc[10];
#pragma unroll
    for (int k = 0; k < 10; ++k) acc[k] = bfo;
#pragma unroll
    for (int J = 0; J < 40; ++J) {
      const float4 v = *(const float4*)(sp + 4 * J);   // bcast in 16-group
#pragma unroll
      for (int e = 0; e < 4; ++e) {
        const int r = 4 * J + e, d = r / 10, k = r - d * 10;
        acc[k] = fmaf(wfo[d], f4e(v, e), acc[k]);
      }
    }

    // fused reduce+select logits (R15/R16-verified math)
    float lj = 0.f;
#pragma unroll
    for (int k = 0; k < 10; ++k) {
      const float s = sum16(w1o * acc[k]);   // = sb + a2[k], all lanes
      lj = (k == f) ? s : lj;
    }
    lj += sum16(u_own * xo) + addA;

    if (f < 10) {
      out0[(size_t)pt * 16 + f] = lj;   // stash logit; K3 overwrites
      const float M = fmaxf(rm, lj);    // branchless online (m,s)
      rs = rs * __expf(rm - M) + __expf(lj - M);
      rm = M;
    }

    // ---- h2: overwrite own (dead) tile row in h2 layout, then packed store --
    // acc depends on ALL 40 row reads => writes are data-dep ordered after them
    __builtin_amdgcn_wave_barrier();
    {
      float* hrow = &sm[cur][g * ROWF + 10 * f];
      *(float2*)(hrow + 0) = make_float2(acc[0], acc[1]);
      *(float2*)(hrow + 2) = make_float2(acc[2], acc[3]);
      *(float2*)(hrow + 4) = make_float2(acc[4], acc[5]);
      *(float2*)(hrow + 6) = make_float2(acc[6], acc[7]);
      *(float2*)(hrow + 8) = make_float2(acc[8], acc[9]);
    }
    __builtin_amdgcn_wave_barrier();   // own-wave rows only; in-order DS
    {
      float* gdst = out1 + (size_t)t * (TPTS * 160);
      const float4 v0 = *(const float4*)(&sm[cur][rb0]);
      const float4 v1 = *(const float4*)(&sm[cur][rb1]);
      *(float4*)(gdst + gb0) = v0;     // fully packed: 1KB/instr per wave
      *(float4*)(gdst + gb1) = v1;
      if (hr2) {
        const float4 v2 = *(const float4*)(&sm[cur][rb2]);
        *(float4*)(gdst + gb2) = v2;
      }
    }

    // ---- write-late: land next tile into the OTHER buffer ----
    if (more) {
      *(float4*)(&sm[cur ^ 1][l0]) = st0;
      *(float4*)(&sm[cur ^ 1][l1]) = st1;
      if (has2) *(float4*)(&sm[cur ^ 1][l2]) = st2;
    }
    cur ^= 1;
  }

  // (m,s): combine the 4 point-subgroups (lane bits 4,5), then 4 waves
  {
    float om = __shfl_xor(rm, 16), os = __shfl_xor(rs, 16);
    comb(rm, rs, om, os);
    om = __shfl_xor(rm, 32); os = __shfl_xor(rs, 32);
    comb(rm, rs, om, os);
  }
  if (lane < 10) {
    s_red[wave][lane][0] = rm;
    s_red[wave][lane][1] = rs;
  }
  __syncthreads();
  if (tid < 10) {
    float m = s_red[0][tid][0], s = s_red[0][tid][1];
    comb(m, s, s_red[1][tid][0], s_red[1][tid][1]);
    comb(m, s, s_red[2][tid][0], s_red[2][tid][1]);
    comb(m, s, s_red[3][tid][0], s_red[3][tid][1]);
    partials[(size_t)blockIdx.x * 20 + tid * 2 + 0] = m;
    partials[(size_t)blockIdx.x * 20 + tid * 2 + 1] = s;
  }
}

__global__ __launch_bounds__(256) void gap_k2(const float* __restrict__ part,
                                              int nb, float* __restrict__ fin) {
  const int k = blockIdx.x;   // one block per k-slot
  const int tid = threadIdx.x;
  float m = -INFINITY, s = 0.f;
  for (int i = tid; i < nb; i += 256)
    comb(m, s, part[(size_t)i * 20 + k * 2], part[(size_t)i * 20 + k * 2 + 1]);
#pragma unroll
  for (int mask = 1; mask < 64; mask <<= 1) {
    float om = __shfl_xor(m, mask, 64);
    float os = __shfl_xor(s, mask, 64);
    comb(m, s, om, os);
  }
  __shared__ float sm[4][2];
  const int wave = tid >> 6, lane = tid & 63;
  if (lane == 0) { sm[wave][0] = m; sm[wave][1] = s; }
  __syncthreads();
  if (tid == 0) {
    for (int w = 1; w < 4; ++w) comb(m, s, sm[w][0], sm[w][1]);
    fin[k * 2 + 0] = m;
    fin[k * 2 + 1] = s;
  }
}

// K3: 4 lanes per point; lane (p,q) accumulates features f = 4q..4q+3.
// Reads out1 flat at offset k*16+f == x2v[k][f] (raw-reshape identity).
__global__ __launch_bounds__(256) void gap_k3(const float* __restrict__ fin,
                                              float* __restrict__ out, int n) {
  __shared__ float s_fin[20];
  if (threadIdx.x < 20) s_fin[threadIdx.x] = fin[threadIdx.x];
  __syncthreads();
  float mk[10], rsk[10];
#pragma unroll
  for (int k = 0; k < 10; ++k) {
    mk[k] = s_fin[2 * k];
    rsk[k] = 1.0f / s_fin[2 * k + 1];
  }
  float* out0 = out;
  const float* out1 = out + (size_t)n * 16;
  const int q = threadIdx.x & 3;
  const int pl = threadIdx.x >> 2;           // 64 points per block pass
  for (long i = (long)blockIdx.x * 64 + pl; i < n; i += (long)gridDim.x * 64) {
    float* lrow = out0 + i * 16;
    // all 4 lanes of the quad read the same 64B logit line (L1 broadcast)
    float4 la = *(const float4*)(lrow);
    float4 lb = *(const float4*)(lrow + 4);
    float2 lc = *(const float2*)(lrow + 8);
    float l[10] = {la.x, la.y, la.z, la.w, lb.x, lb.y, lb.z, lb.w, lc.x, lc.y};
    float w[10];
#pragma unroll
    for (int k = 0; k < 10; ++k) w[k] = __expf(l[k] - mk[k]) * rsk[k];
    const float* vrow = out1 + i * 160 + q * 4;
    float4 acc = make_float4(0.f, 0.f, 0.f, 0.f);
#pragma unroll
    for (int k = 0; k < 10; ++k) {
      float4 v = *(const float4*)(vrow + k * 16);
      float wk = w[k];
      acc.x = fmaf(wk, v.x, acc.x);
      acc.y = fmaf(wk, v.y, acc.y);
      acc.z = fmaf(wk, v.z, acc.z);
      acc.w = fmaf(wk, v.w, acc.w);
    }
    // store after all reads (wave-lockstep => no RAW hazard on the logit line)
    *(float4*)(lrow + q * 4) = acc;
  }
}

extern "C" void kernel_launch(void* const* d_in, const int* in_sizes, int n_in,
                              void* d_out, int out_size, void* d_ws, size_t ws_size,
                              hipStream_t stream) {
  const float* xknn = (const float*)d_in[0];
  const float* x    = (const float*)d_in[1];
  const float* Wf   = (const float*)d_in[2];
  const float* bf   = (const float*)d_in[3];
  const float* W1   = (const float*)d_in[4];
  const float* b1   = (const float*)d_in[5];
  float* out = (float*)d_out;
  const int n = in_sizes[1] / 16;  // x is [N][16]

  const int G1 = 1792;   // 7 blocks/CU x 256 CU
  float* partials = (float*)d_ws;                 // [G1][10][2]
  float* finals = partials + (size_t)G1 * 20;     // [10][2]

  gap_k1<<<G1, 256, 0, stream>>>(xknn, x, Wf, bf, W1, b1, out, partials, n);
  gap_k2<<<10, 256, 0, stream>>>(partials, G1, finals);
  gap_k3<<<2048, 256, 0, stream>>>(finals, out, n);
}

// Round 19
// 469.777 us; speedup vs baseline: 1.0641x; 1.0641x over previous
//
#include <hip/hip_runtime.h>
#include <math.h>

// SingleGAP: per-point tiny MLPs + GLOBAL softmax over N (axis 0, faithful bug),
// then attention-weighted sum. out0 = [N][16] x_attn, out1 = [N][160] h2 (flat,
// [F][K] order per point == x2v raw reshape).
//
// R19 two-pass re-partition:
//   K1 (LIGHT): logits + (m,s) only, via u = W1^T Wf (no h2!). Quad-per-point,
//       per-lane contiguous 40-float quarter (R4-proven clean loads), 40 FMA +
//       quad butterfly. Reads 704MB, writes 64MB logits + tiny partials.
//   K2: reduce per-block (m,s) -> global (m,s) per k-slot (unchanged).
//   K3 (HEAVY): R17's staged h2 sweep + fused weight-apply. Reads xknn+logits,
//       recomputes h2, writes h2 -> out1 and x_attn -> out0. No reductions at
//       all (the sum16/a1/(m,s) machinery lives in K1 where it's cheap).

#define TPTS 16              // K3 points per tile
#define ROWF 164             // padded floats per point row (40 float4 + 1 pad)

__device__ __forceinline__ void comb(float& m, float& s, float om, float os) {
  float M = fmaxf(m, om);
  if (M == -INFINITY) return;  // both empty
  s = s * __expf(m - M) + os * __expf(om - M);
  m = M;
}

__device__ __forceinline__ float f4e(const float4& v, int e) {
  return (e == 0) ? v.x : (e == 1) ? v.y : (e == 2) ? v.z : v.w;
}

// ---------------- K1: light logits pass (quad-per-point, u-trick) ----------
__global__ __launch_bounds__(256) void gap_k1(
    const float* __restrict__ xknn, const float* __restrict__ x,
    const float* __restrict__ Wf, const float* __restrict__ bf,
    const float* __restrict__ W1, const float* __restrict__ b1p,
    float* __restrict__ out, float* __restrict__ partials, int n) {
  __shared__ float s_red[4][16][2];

  const int tid = threadIdx.x;
  const int q = tid & 3;          // quad lane: owns chunk [40q,40q+40)
  const int lane = tid & 63;
  const int wave = tid >> 6;

  // u4[j] = u[4q+j] = sum_f W1[f] Wf[f][4q+j]  (scalar column reads, prologue)
  float u4[4];
#pragma unroll
  for (int j = 0; j < 4; ++j) {
    float t = 0.f;
#pragma unroll
    for (int ff = 0; ff < 16; ++ff)
      t = fmaf(W1[ff], Wf[ff * 16 + 4 * q + j], t);
    u4[j] = t;
  }
  float sb = 0.f;
#pragma unroll
  for (int ff = 0; ff < 16; ++ff) sb = fmaf(W1[ff], bf[ff], sb);
  const float addK = 2.0f * (sb + b1p[0]);  // logit = pa[k] + a1u + addK

  // online softmax state for owned k = 4q+j (invalid slots stay empty)
  float rm[4] = {-INFINITY, -INFINITY, -INFINITY, -INFINITY};
  float rs[4] = {0.f, 0.f, 0.f, 0.f};

  float* out0 = out;   // [n][16]: logits stash (K3 reads then overwrites)

  const long pt0 = (long)blockIdx.x * 64 + (tid >> 2);
  const long pstride = (long)gridDim.x * 64;

  for (long pt = pt0; pt < n; pt += pstride) {
    // own quarter: contiguous 160B per lane (R4-counter-proven clean)
    const float* rowq = xknn + (size_t)pt * 160 + 40 * q;
    float4 own[10];   // unconditional compile-time-indexed: no promote-alloca
#pragma unroll
    for (int j = 0; j < 10; ++j) own[j] = *(const float4*)(rowq + 4 * j);
    const float4 xc4 = *(const float4*)(x + (size_t)pt * 16 + 4 * q);

    // pa[k] = sum_{j<4} u4[j] * chunk[10j+k]  (chunk rows d = 4q..4q+3)
    float pa[10];
#pragma unroll
    for (int k = 0; k < 10; ++k) {
      float t = u4[0] * f4e(own[k >> 2], k & 3);
      t = fmaf(u4[1], f4e(own[(10 + k) >> 2], (10 + k) & 3), t);
      t = fmaf(u4[2], f4e(own[(20 + k) >> 2], (20 + k) & 3), t);
      t = fmaf(u4[3], f4e(own[(30 + k) >> 2], (30 + k) & 3), t);
      pa[k] = t;
    }
#pragma unroll
    for (int k = 0; k < 10; ++k) pa[k] += __shfl_xor(pa[k], 1);
#pragma unroll
    for (int k = 0; k < 10; ++k) pa[k] += __shfl_xor(pa[k], 2);

    float a1u = u4[0] * xc4.x;
    a1u = fmaf(u4[1], xc4.y, a1u);
    a1u = fmaf(u4[2], xc4.z, a1u);
    a1u = fmaf(u4[3], xc4.w, a1u);
    a1u += __shfl_xor(a1u, 1);
    a1u += __shfl_xor(a1u, 2);
    const float addc = a1u + addK;

    // lane q takes logits k=4q..4q+3 (cndmask chain; R3/R4-verified)
    float lj[4];
#pragma unroll
    for (int j = 0; j < 4; ++j) {
      const int k = 4 * q + j;  // runtime q
      float v = 0.f;
#pragma unroll
      for (int kk = 0; kk < 10; ++kk) v = (kk == k) ? (pa[kk] + addc) : v;
      lj[j] = v;
      if (k < 10) comb(rm[j], rs[j], v, 1.0f);
    }
    *(float4*)(out0 + (size_t)pt * 16 + 4 * q) =
        make_float4(lj[0], lj[1], lj[2], lj[3]);
  }

  // reduce (m,s) across the wave's 16 quads (lanes differing in bits 2..5)
#pragma unroll
  for (int mask = 4; mask < 64; mask <<= 1) {
#pragma unroll
    for (int j = 0; j < 4; ++j) {
      float om = __shfl_xor(rm[j], mask);
      float os = __shfl_xor(rs[j], mask);
      comb(rm[j], rs[j], om, os);
    }
  }
  if (lane < 4) {  // slot index k = 4*lane + j
#pragma unroll
    for (int j = 0; j < 4; ++j) {
      s_red[wave][lane * 4 + j][0] = rm[j];
      s_red[wave][lane * 4 + j][1] = rs[j];
    }
  }
  __syncthreads();
  if (tid < 10) {
    float m = s_red[0][tid][0], s = s_red[0][tid][1];
    comb(m, s, s_red[1][tid][0], s_red[1][tid][1]);
    comb(m, s, s_red[2][tid][0], s_red[2][tid][1]);
    comb(m, s, s_red[3][tid][0], s_red[3][tid][1]);
    partials[(size_t)blockIdx.x * 20 + tid * 2 + 0] = m;
    partials[(size_t)blockIdx.x * 20 + tid * 2 + 1] = s;
  }
}

// ---------------- K2: merge per-block (m,s) ----------------
__global__ __launch_bounds__(256) void gap_k2(const float* __restrict__ part,
                                              int nb, float* __restrict__ fin) {
  const int k = blockIdx.x;   // one block per k-slot
  const int tid = threadIdx.x;
  float m = -INFINITY, s = 0.f;
  for (int i = tid; i < nb; i += 256)
    comb(m, s, part[(size_t)i * 20 + k * 2], part[(size_t)i * 20 + k * 2 + 1]);
#pragma unroll
  for (int mask = 1; mask < 64; mask <<= 1) {
    float om = __shfl_xor(m, mask, 64);
    float os = __shfl_xor(s, mask, 64);
    comb(m, s, om, os);
  }
  __shared__ float sm[4][2];
  const int wave = tid >> 6, lane = tid & 63;
  if (lane == 0) { sm[wave][0] = m; sm[wave][1] = s; }
  __syncthreads();
  if (tid == 0) {
    for (int w = 1; w < 4; ++w) comb(m, s, sm[w][0], sm[w][1]);
    fin[k * 2 + 0] = m;
    fin[k * 2 + 1] = s;
  }
}

// ---------------- K3: heavy h2 + fused weighted sum ----------------
__global__ __launch_bounds__(256) void gap_k3(
    const float* __restrict__ xknn, const float* __restrict__ Wf,
    const float* __restrict__ bf, const float* __restrict__ fin,
    float* out, int n) {
  __shared__ float sm[2][TPTS * ROWF];   // 2 x 16 x 164 floats = 21 KB
  __shared__ float s_mk[10], s_rk[10];

  const int tid = threadIdx.x;
  const int f = (tid & 63) & 15;  // owned feature
  const int g = tid >> 4;         // point-in-tile 0..15

  if (tid < 10) {
    s_mk[tid] = fin[2 * tid];
    s_rk[tid] = 1.0f / fin[2 * tid + 1];
  }

  // staging geometry (R17-verified): F4 indices tid, tid+256, tid+512(<640)
  const int F0 = tid, F1 = tid + 256, F2 = tid + 512;
  const unsigned l0 = (unsigned)((F0 / 40) * ROWF + (F0 % 40) * 4);
  const unsigned l1 = (unsigned)((F1 / 40) * ROWF + (F1 % 40) * 4);
  const unsigned l2 = (unsigned)((F2 / 40) * ROWF + (F2 % 40) * 4);
  const bool has2 = (F2 < TPTS * 40);    // tid < 128

  // own Wf row f (16 VGPR), bf[f]
  float wfo[16];
#pragma unroll
  for (int dq = 0; dq < 4; ++dq) {
    float4 v = *(const float4*)(Wf + f * 16 + 4 * dq);
    wfo[4 * dq + 0] = v.x;
    wfo[4 * dq + 1] = v.y;
    wfo[4 * dq + 2] = v.z;
    wfo[4 * dq + 3] = v.w;
  }
  const float bfo = bf[f];

  float* out0 = out;                       // [n][16]: logits in, x_attn out
  float* out1 = out + (size_t)n * 16;      // [n][160] h2 flat

  const long ntiles = (long)n / TPTS;      // n = 1M: exact
  const long G = gridDim.x;
  long t = (long)blockIdx.x;
  int cur = 0;

  float4 st0, st1, st2;                    // NAMED staging regs (R14 lesson)

  // prologue: stage first tile into buf 0
  {
    const float* src = xknn + (size_t)t * (TPTS * 160);
    st0 = *(const float4*)(src + 4 * F0);
    st1 = *(const float4*)(src + 4 * F1);
    st2 = st0;
    if (has2) st2 = *(const float4*)(src + 4 * F2);
    *(float4*)(&sm[0][l0]) = st0;
    *(float4*)(&sm[0][l1]) = st1;
    if (has2) *(float4*)(&sm[0][l2]) = st2;
  }

  for (; t < ntiles; t += G) {
    __syncthreads();                  // buf[cur] staged & prior readers done

    const long tn = t + G;
    const bool more = (tn < ntiles);
    if (more) {                       // issue-early; in flight under compute
      const float* src = xknn + (size_t)tn * (TPTS * 160);
      st0 = *(const float4*)(src + 4 * F0);
      st1 = *(const float4*)(src + 4 * F1);
      if (has2) st2 = *(const float4*)(src + 4 * F2);
    }

    // ---- h2 for point pt = t*16 + g from buf[cur] ----
    const unsigned pt = (unsigned)t * TPTS + (unsigned)g;
    const float* sp = &sm[cur][g * ROWF];

    float acc[10];
#pragma unroll
    for (int k = 0; k < 10; ++k) acc[k] = bfo;
#pragma unroll
    for (int J = 0; J < 40; ++J) {
      const float4 v = *(const float4*)(sp + 4 * J);   // bcast in 16-group
#pragma unroll
      for (int e = 0; e < 4; ++e) {
        const int r = 4 * J + e, d = r / 10, k = r - d * 10;
        acc[k] = fmaf(wfo[d], f4e(v, e), acc[k]);
      }
    }

    // h2 -> out1 flat [F][K]: lane's contiguous [10f,10f+10) (proven clean)
    float* o1 = out1 + ((size_t)pt * 160 + 10 * f);
    *(float2*)(o1 + 0) = make_float2(acc[0], acc[1]);
    *(float2*)(o1 + 2) = make_float2(acc[2], acc[3]);
    *(float2*)(o1 + 4) = make_float2(acc[4], acc[5]);
    *(float2*)(o1 + 6) = make_float2(acc[6], acc[7]);
    *(float2*)(o1 + 8) = make_float2(acc[8], acc[9]);

    // ---- fused weight-apply: x_attn[f] = sum_k w[k] h2[f][k] ----
    // all 16 lanes read the point's 40B logit row (same 64B line: L1 bcast)
    const float* lrow = out0 + (size_t)pt * 16;
    const float4 la = *(const float4*)(lrow);
    const float4 lb = *(const float4*)(lrow + 4);
    const float2 lc = *(const float2*)(lrow + 8);
    float xa = 0.f;
#pragma unroll
    for (int k = 0; k < 10; ++k) {
      const float lv = (k < 4) ? f4e(la, k & 3)
                     : (k < 8) ? f4e(lb, k & 3)
                     : (k == 8) ? lc.x : lc.y;
      const float wk = __expf(lv - s_mk[k]) * s_rk[k];
      xa = fmaf(wk, acc[k], xa);
    }
    out0[(size_t)pt * 16 + f] = xa;   // after the row reads (in-order wave)

    // ---- write-late: land next tile into the OTHER buffer ----
    if (more) {
      *(float4*)(&sm[cur ^ 1][l0]) = st0;
      *(float4*)(&sm[cur ^ 1][l1]) = st1;
      if (has2) *(float4*)(&sm[cur ^ 1][l2]) = st2;
    }
    cur ^= 1;
  }
}

extern "C" void kernel_launch(void* const* d_in, const int* in_sizes, int n_in,
                              void* d_out, int out_size, void* d_ws, size_t ws_size,
                              hipStream_t stream) {
  const float* xknn = (const float*)d_in[0];
  const float* x    = (const float*)d_in[1];
  const float* Wf   = (const float*)d_in[2];
  const float* bf   = (const float*)d_in[3];
  const float* W1   = (const float*)d_in[4];
  const float* b1   = (const float*)d_in[5];
  float* out = (float*)d_out;
  const int n = in_sizes[1] / 16;  // x is [N][16]

  const int G1 = 2048;
  float* partials = (float*)d_ws;                 // [G1][10][2]
  float* finals = partials + (size_t)G1 * 20;     // [10][2]

  gap_k1<<<G1, 256, 0, stream>>>(xknn, x, Wf, bf, W1, b1, out, partials, n);
  gap_k2<<<10, 256, 0, stream>>>(partials, G1, finals);
  gap_k3<<<1792, 256, 0, stream>>>(xknn, Wf, bf, finals, out, n);
}

// Round 20
// 468.064 us; speedup vs baseline: 1.0680x; 1.0037x over previous
//
#include <hip/hip_runtime.h>
#include <math.h>

// SingleGAP: per-point tiny MLPs + GLOBAL softmax over N (axis 0, faithful bug),
// then attention-weighted sum. out0 = [N][16] x_attn, out1 = [N][160] h2 (flat,
// [F][K] order per point == x2v raw reshape).
//
// R20:
//   K1 (LIGHT, octet): logits + (m,s) via u = W1^T Wf. Lane o of 8 owns flat
//       slice [20o,20o+20) = x2 rows d={2o,2o+1} -> pa partial = 20 FMA with
//       u2[2]; 8-lane butterflies. 5 NAMED float4s -> ~56 VGPR -> 8 waves/SIMD
//       (occupancy->BW: R13 proved 47% occ delivers 4.6+ TB/s).
//   K2: reduce per-block (m,s) -> global (m,s) per k-slot (unchanged).
//   K3 (HEAVY): R19-verified staged h2 sweep + fused weight-apply (unchanged).

#define TPTS 16              // K3 points per tile
#define ROWF 164             // padded floats per point row (40 float4 + 1 pad)

__device__ __forceinline__ void comb(float& m, float& s, float om, float os) {
  float M = fmaxf(m, om);
  if (M == -INFINITY) return;  // both empty
  s = s * __expf(m - M) + os * __expf(om - M);
  m = M;
}

__device__ __forceinline__ float f4e(const float4& v, int e) {
  return (e == 0) ? v.x : (e == 1) ? v.y : (e == 2) ? v.z : v.w;
}

// ---------------- K1: light logits pass (octet-per-point, u-trick) ---------
__global__ __launch_bounds__(256) void gap_k1(
    const float* __restrict__ xknn, const float* __restrict__ x,
    const float* __restrict__ Wf, const float* __restrict__ bf,
    const float* __restrict__ W1, const float* __restrict__ b1p,
    float* __restrict__ out, float* __restrict__ partials, int n) {
  __shared__ float s_red[4][16][2];

  const int tid = threadIdx.x;
  const int o = tid & 7;          // octet lane: owns flat [20o,20o+20)
  const int lane = tid & 63;
  const int wave = tid >> 6;

  // u2[j] = u[2o+j] = sum_f W1[f] Wf[f][2o+j]  (scalar reads, prologue-only)
  float u2[2];
#pragma unroll
  for (int j = 0; j < 2; ++j) {
    float t = 0.f;
#pragma unroll
    for (int ff = 0; ff < 16; ++ff)
      t = fmaf(W1[ff], Wf[ff * 16 + 2 * o + j], t);
    u2[j] = t;
  }
  float sb = 0.f;
#pragma unroll
  for (int ff = 0; ff < 16; ++ff) sb = fmaf(W1[ff], bf[ff], sb);
  const float addK = 2.0f * (sb + b1p[0]);  // logit = pa[k] + a1u + addK

  // online softmax state for owned k = {2o, 2o+1} (valid for o<5)
  float rm[2] = {-INFINITY, -INFINITY}, rs[2] = {0.f, 0.f};

  float* out0 = out;   // [n][16]: logits stash (K3 reads then overwrites)

  const long pt0 = (long)blockIdx.x * 32 + (tid >> 3);
  const long pstride = (long)gridDim.x * 32;

  // ownflat[i] for compile-time i in [0,20): component of NAMED own0..own4
#define OF(i) ((i) < 4 ? f4e(own0, (i) & 3)                       \
              : (i) < 8 ? f4e(own1, (i) & 3)                      \
              : (i) < 12 ? f4e(own2, (i) & 3)                     \
              : (i) < 16 ? f4e(own3, (i) & 3) : f4e(own4, (i) & 3))

  for (long pt = pt0; pt < n; pt += pstride) {
    const float* rowq = xknn + (size_t)pt * 160 + 20 * o;
    const float4 own0 = *(const float4*)(rowq + 0);
    const float4 own1 = *(const float4*)(rowq + 4);
    const float4 own2 = *(const float4*)(rowq + 8);
    const float4 own3 = *(const float4*)(rowq + 12);
    const float4 own4 = *(const float4*)(rowq + 16);
    const float2 xc = *(const float2*)(x + (size_t)pt * 16 + 2 * o);

    // pa partial over own 2 d-rows: pa[k] = u[2o]*flat[k] + u[2o+1]*flat[10+k]
    float pa[10];
#pragma unroll
    for (int k = 0; k < 10; ++k)
      pa[k] = fmaf(u2[1], OF(10 + k), u2[0] * OF(k));
    // 8-lane butterfly -> full pa on all lanes (R8-verified masks)
#pragma unroll
    for (int k = 0; k < 10; ++k) pa[k] += __shfl_xor(pa[k], 1);
#pragma unroll
    for (int k = 0; k < 10; ++k) pa[k] += __shfl_xor(pa[k], 2);
#pragma unroll
    for (int k = 0; k < 10; ++k) pa[k] += __shfl_xor(pa[k], 4);

    float a1u = fmaf(u2[1], xc.y, u2[0] * xc.x);
    a1u += __shfl_xor(a1u, 1);
    a1u += __shfl_xor(a1u, 2);
    a1u += __shfl_xor(a1u, 4);
    const float addc = a1u + addK;

    // logits k = {2o, 2o+1} (cndmask chains; R8/R10/R11-verified)
    float lj0 = 0.f, lj1 = 0.f;
#pragma unroll
    for (int kk = 0; kk < 10; ++kk) {
      lj0 = (kk == 2 * o) ? (pa[kk] + addc) : lj0;
      lj1 = (kk == 2 * o + 1) ? (pa[kk] + addc) : lj1;
    }
    *(float2*)(out0 + (size_t)pt * 16 + 2 * o) = make_float2(lj0, lj1);
    if (o < 5) {
      comb(rm[0], rs[0], lj0, 1.0f);
      comb(rm[1], rs[1], lj1, 1.0f);
    }
  }
#undef OF

  // (m,s) reduce across the wave's 8 points (lane bits 3..5), then block
#pragma unroll
  for (int mk = 8; mk < 64; mk <<= 1) {
#pragma unroll
    for (int j = 0; j < 2; ++j) {
      float om = __shfl_xor(rm[j], mk);
      float os = __shfl_xor(rs[j], mk);
      comb(rm[j], rs[j], om, os);
    }
  }
  if (lane < 5) {
#pragma unroll
    for (int j = 0; j < 2; ++j) {
      s_red[wave][2 * lane + j][0] = rm[j];
      s_red[wave][2 * lane + j][1] = rs[j];
    }
  }
  __syncthreads();
  if (tid < 10) {
    float m = s_red[0][tid][0], s = s_red[0][tid][1];
    comb(m, s, s_red[1][tid][0], s_red[1][tid][1]);
    comb(m, s, s_red[2][tid][0], s_red[2][tid][1]);
    comb(m, s, s_red[3][tid][0], s_red[3][tid][1]);
    partials[(size_t)blockIdx.x * 20 + tid * 2 + 0] = m;
    partials[(size_t)blockIdx.x * 20 + tid * 2 + 1] = s;
  }
}

// ---------------- K2: merge per-block (m,s) ----------------
__global__ __launch_bounds__(256) void gap_k2(const float* __restrict__ part,
                                              int nb, float* __restrict__ fin) {
  const int k = blockIdx.x;   // one block per k-slot
  const int tid = threadIdx.x;
  float m = -INFINITY, s = 0.f;
  for (int i = tid; i < nb; i += 256)
    comb(m, s, part[(size_t)i * 20 + k * 2], part[(size_t)i * 20 + k * 2 + 1]);
#pragma unroll
  for (int mask = 1; mask < 64; mask <<= 1) {
    float om = __shfl_xor(m, mask, 64);
    float os = __shfl_xor(s, mask, 64);
    comb(m, s, om, os);
  }
  __shared__ float sm[4][2];
  const int wave = tid >> 6, lane = tid & 63;
  if (lane == 0) { sm[wave][0] = m; sm[wave][1] = s; }
  __syncthreads();
  if (tid == 0) {
    for (int w = 1; w < 4; ++w) comb(m, s, sm[w][0], sm[w][1]);
    fin[k * 2 + 0] = m;
    fin[k * 2 + 1] = s;
  }
}

// ---------------- K3: heavy h2 + fused weighted sum (R19-verified) ---------
__global__ __launch_bounds__(256) void gap_k3(
    const float* __restrict__ xknn, const float* __restrict__ Wf,
    const float* __restrict__ bf, const float* __restrict__ fin,
    float* out, int n) {
  __shared__ float sm[2][TPTS * ROWF];   // 2 x 16 x 164 floats = 21 KB
  __shared__ float s_mk[10], s_rk[10];

  const int tid = threadIdx.x;
  const int f = (tid & 63) & 15;  // owned feature
  const int g = tid >> 4;         // point-in-tile 0..15

  if (tid < 10) {
    s_mk[tid] = fin[2 * tid];
    s_rk[tid] = 1.0f / fin[2 * tid + 1];
  }

  // staging geometry (R17-verified): F4 indices tid, tid+256, tid+512(<640)
  const int F0 = tid, F1 = tid + 256, F2 = tid + 512;
  const unsigned l0 = (unsigned)((F0 / 40) * ROWF + (F0 % 40) * 4);
  const unsigned l1 = (unsigned)((F1 / 40) * ROWF + (F1 % 40) * 4);
  const unsigned l2 = (unsigned)((F2 / 40) * ROWF + (F2 % 40) * 4);
  const bool has2 = (F2 < TPTS * 40);    // tid < 128

  // own Wf row f (16 VGPR), bf[f]
  float wfo[16];
#pragma unroll
  for (int dq = 0; dq < 4; ++dq) {
    float4 v = *(const float4*)(Wf + f * 16 + 4 * dq);
    wfo[4 * dq + 0] = v.x;
    wfo[4 * dq + 1] = v.y;
    wfo[4 * dq + 2] = v.z;
    wfo[4 * dq + 3] = v.w;
  }
  const float bfo = bf[f];

  float* out0 = out;                       // [n][16]: logits in, x_attn out
  float* out1 = out + (size_t)n * 16;      // [n][160] h2 flat

  const long ntiles = (long)n / TPTS;      // n = 1M: exact
  const long G = gridDim.x;
  long t = (long)blockIdx.x;
  int cur = 0;

  float4 st0, st1, st2;                    // NAMED staging regs (R14 lesson)

  // prologue: stage first tile into buf 0
  {
    const float* src = xknn + (size_t)t * (TPTS * 160);
    st0 = *(const float4*)(src + 4 * F0);
    st1 = *(const float4*)(src + 4 * F1);
    st2 = st0;
    if (has2) st2 = *(const float4*)(src + 4 * F2);
    *(float4*)(&sm[0][l0]) = st0;
    *(float4*)(&sm[0][l1]) = st1;
    if (has2) *(float4*)(&sm[0][l2]) = st2;
  }

  for (; t < ntiles; t += G) {
    __syncthreads();                  // buf[cur] staged & prior readers done

    const long tn = t + G;
    const bool more = (tn < ntiles);
    if (more) {                       // issue-early; in flight under compute
      const float* src = xknn + (size_t)tn * (TPTS * 160);
      st0 = *(const float4*)(src + 4 * F0);
      st1 = *(const float4*)(src + 4 * F1);
      if (has2) st2 = *(const float4*)(src + 4 * F2);
    }

    // ---- h2 for point pt = t*16 + g from buf[cur] ----
    const unsigned pt = (unsigned)t * TPTS + (unsigned)g;
    const float* sp = &sm[cur][g * ROWF];

    float acc[10];
#pragma unroll
    for (int k = 0; k < 10; ++k) acc[k] = bfo;
#pragma unroll
    for (int J = 0; J < 40; ++J) {
      const float4 v = *(const float4*)(sp + 4 * J);   // bcast in 16-group
#pragma unroll
      for (int e = 0; e < 4; ++e) {
        const int r = 4 * J + e, d = r / 10, k = r - d * 10;
        acc[k] = fmaf(wfo[d], f4e(v, e), acc[k]);
      }
    }

    // h2 -> out1 flat [F][K]: lane's contiguous [10f,10f+10) (proven clean)
    float* o1 = out1 + ((size_t)pt * 160 + 10 * f);
    *(float2*)(o1 + 0) = make_float2(acc[0], acc[1]);
    *(float2*)(o1 + 2) = make_float2(acc[2], acc[3]);
    *(float2*)(o1 + 4) = make_float2(acc[4], acc[5]);
    *(float2*)(o1 + 6) = make_float2(acc[6], acc[7]);
    *(float2*)(o1 + 8) = make_float2(acc[8], acc[9]);

    // ---- fused weight-apply: x_attn[f] = sum_k w[k] h2[f][k] ----
    const float* lrow = out0 + (size_t)pt * 16;
    const float4 la = *(const float4*)(lrow);
    const float4 lb = *(const float4*)(lrow + 4);
    const float2 lc = *(const float2*)(lrow + 8);
    float xa = 0.f;
#pragma unroll
    for (int k = 0; k < 10; ++k) {
      const float lv = (k < 4) ? f4e(la, k & 3)
                     : (k < 8) ? f4e(lb, k & 3)
                     : (k == 8) ? lc.x : lc.y;
      const float wk = __expf(lv - s_mk[k]) * s_rk[k];
      xa = fmaf(wk, acc[k], xa);
    }
    out0[(size_t)pt * 16 + f] = xa;   // after the row reads (in-order wave)

    // ---- write-late: land next tile into the OTHER buffer ----
    if (more) {
      *(float4*)(&sm[cur ^ 1][l0]) = st0;
      *(float4*)(&sm[cur ^ 1][l1]) = st1;
      if (has2) *(float4*)(&sm[cur ^ 1][l2]) = st2;
    }
    cur ^= 1;
  }
}

extern "C" void kernel_launch(void* const* d_in, const int* in_sizes, int n_in,
                              void* d_out, int out_size, void* d_ws, size_t ws_size,
                              hipStream_t stream) {
  const float* xknn = (const float*)d_in[0];
  const float* x    = (const float*)d_in[1];
  const float* Wf   = (const float*)d_in[2];
  const float* bf   = (const float*)d_in[3];
  const float* W1   = (const float*)d_in[4];
  const float* b1   = (const float*)d_in[5];
  float* out = (float*)d_out;
  const int n = in_sizes[1] / 16;  // x is [N][16]

  const int G1 = 2048;
  float* partials = (float*)d_ws;                 // [G1][10][2]
  float* finals = partials + (size_t)G1 * 20;     // [10][2]

  gap_k1<<<G1, 256, 0, stream>>>(xknn, x, Wf, bf, W1, b1, out, partials, n);
  gap_k2<<<10, 256, 0, stream>>>(partials, G1, finals);
  gap_k3<<<1792, 256, 0, stream>>>(xknn, Wf, bf, finals, out, n);
}